// Round 1
// 235.690 us; speedup vs baseline: 1.0105x; 1.0105x over previous
//
#include <hip/hip_runtime.h>
#include <hip/hip_bf16.h>
#include <math.h>

// Problem constants (GraphAttentionReadout)
#define BB 128      // batch
#define NN 2048     // nodes
#define ND 128      // NODE_DIM
#define QD 256      // QUERY_DIM
#define OD 256      // OUT_DIM

// R8 decomposition: 8 blocks per batch, 256 rows per block, 64 rows per wave,
// streamed as 8 double-buffered steps of 8 rows (4 KB) per wave.
#define NPART 8                       // blocks (=partials) per batch
#define ROWS_PER_BLOCK (NN / NPART)   // 256
#define ROWS_PER_WAVE  (ROWS_PER_BLOCK / 4)  // 64
#define STEPS 8
#define STEP_ROWS (ROWS_PER_WAVE / STEPS)    // 8
#define STEP_BYTES (STEP_ROWS * ND * 4)      // 4096
#define PART_STRIDE 260               // l1,l2,(2 spare), W1[128], W2[128]

// hardware v_exp_f32 computes 2^x directly (~1 ULP)
#define EXP2F(x) __builtin_amdgcn_exp2f(x)

typedef __attribute__((address_space(1))) const void gvoid_t;
typedef __attribute__((address_space(3))) void lvoid_t;

// ---------------------------------------------------------------------------
// Kernel 1: per-batch projections.
//   qk{1,2} = (fp @ Wq{1,2}.T) @ Wk * inv_scale * log2(e)
// ---------------------------------------------------------------------------
__global__ __launch_bounds__(128) void proj_kernel(
    const float* __restrict__ fp_vec, const float* __restrict__ Wq1,
    const float* __restrict__ Wq2, const float* __restrict__ Wk,
    float* __restrict__ qk1g, float* __restrict__ qk2g)
{
  __shared__ __align__(16) float fp_s[QD];
  __shared__ float q1_s[ND];
  __shared__ float q2_s[ND];
  const int b = blockIdx.x, t = threadIdx.x;
  fp_s[t]       = fp_vec[b * QD + t];
  fp_s[t + 128] = fp_vec[b * QD + 128 + t];
  __syncthreads();
  float a1 = 0.f, a2 = 0.f;
  const float4* w1p = (const float4*)(Wq1 + t * QD);
  const float4* w2p = (const float4*)(Wq2 + t * QD);
  #pragma unroll 8
  for (int q = 0; q < QD / 4; ++q) {
    float4 wa = w1p[q], wb = w2p[q];
    float4 f = *(const float4*)&fp_s[q * 4];
    a1 += f.x * wa.x + f.y * wa.y + f.z * wa.z + f.w * wa.w;
    a2 += f.x * wb.x + f.y * wb.y + f.z * wb.z + f.w * wb.w;
  }
  q1_s[t] = a1;
  q2_s[t] = a2;
  __syncthreads();
  float k1 = 0.f, k2 = 0.f;
  #pragma unroll 8
  for (int e = 0; e < ND; ++e) {
    float wv = Wk[e * ND + t];   // coalesced across threads
    k1 += q1_s[e] * wv;
    k2 += q2_s[e] * wv;
  }
  // 1/sqrt(128) * log2(e)
  const float cscale = 0.08838834764831845f * 1.4426950408889634f;
  qk1g[b * ND + t] = k1 * cscale;
  qk2g[b * ND + t] = k2 * cscale;
}

// ---------------------------------------------------------------------------
// Kernel 2 (R8): barrier-free, wave-autonomous streaming softmax pass.
//
// R1-R7 all plateaued at ~75 us (~1.78 TB/s read) across five staging
// mechanisms including the R7 global_load_lds DMA. The shared invariant was
// the lockstep block lifecycle: one DMA burst -> __syncthreads (implicit
// vmcnt(0) drain) -> compute with memory idle -> epilogue barriers -> block
// death/relaunch, with all resident blocks phase-aligned. R8 removes every
// mid-kernel barrier: each wave is an independent double-buffered pipeline
// (T3/T4 counted-vmcnt discipline; vmcnt never drained to 0 until the tail),
// so per CU ~128 KB of DMA stays in flight continuously.
//
// Grid: BB*NPART = 1024 blocks (exactly 4/CU at 36 KB LDS), 256 threads.
// Wave w owns rows [oct*256 + w*64, +64) of batch b, streamed as 8 steps of
// 8 rows into tile_s[w][step&1]. Per row-pair j: float4/lane dot, packed-
// parity shuffle tree (7 shuffles vs 10), exp2-domain softmax accumulation.
// One __syncthreads only at the final cross-wave partial reduction.
// ---------------------------------------------------------------------------
__global__ __launch_bounds__(256, 4) void attn_kernel(
    const float* __restrict__ node, const int* __restrict__ mask,
    const float* __restrict__ qk1g, const float* __restrict__ qk2g,
    float* __restrict__ part)
{
  const int bid = blockIdx.x;
  const int b   = bid >> 3;            // bid / NPART
  const int oct = bid & (NPART - 1);
  const int t = threadIdx.x;
  const int w = t >> 6;
  const int lane = t & 63;
  const int half = lane >> 5;          // 0: even row of pair, 1: odd row
  const int hl = lane & 31;            // owns d = 4*hl .. 4*hl+3

  __shared__ __align__(16) float tile_s[4][2][STEP_ROWS * ND]; // 32 KB
  __shared__ __align__(16) float sw1[4][ND], sw2[4][ND];       // 4 KB
  __shared__ float sl1[4], sl2[4];

  const int wrow0 = oct * ROWS_PER_BLOCK + w * ROWS_PER_WAVE;  // row in batch

  // pre-loads: issued before any DMA so they retire first (vmcnt in-order)
  const float4 qk1 = *(const float4*)(qk1g + b * ND + hl * 4);
  const float4 qk2 = *(const float4*)(qk2g + b * ND + hl * 4);
  const int mv = mask[b * NN + wrow0 + lane];   // this wave's 64 mask words

  const char* gbase = (const char*)node + (size_t)(b * NN + wrow0) * (ND * 4);
  char* lb0 = (char*)&tile_s[w][0][0];
  char* lb1 = (char*)&tile_s[w][1][0];

  // DMA prologue: steps 0 and 1 (4 x 1 KB each; dest wave-uniform + lane*16)
  #pragma unroll
  for (int i = 0; i < 4; ++i)
    __builtin_amdgcn_global_load_lds(
        (gvoid_t*)(gbase + lane * 16 + i * 1024),
        (lvoid_t*)(lb0 + i * 1024), 16, 0, 0);
  #pragma unroll
  for (int i = 0; i < 4; ++i)
    __builtin_amdgcn_global_load_lds(
        (gvoid_t*)(gbase + STEP_BYTES + lane * 16 + i * 1024),
        (lvoid_t*)(lb1 + i * 1024), 16, 0, 0);

  // additive pad in exp2 domain, one register, broadcast later via shfl
  const float pv = mv ? 0.f : -1e9f;

  float l1 = 0.f, l2 = 0.f;
  float4 w1 = make_float4(0.f, 0.f, 0.f, 0.f);
  float4 w2 = make_float4(0.f, 0.f, 0.f, 0.f);

  #pragma unroll 2
  for (int s = 0; s < STEPS; ++s) {
    // wait for step s's 4 DMAs; keep step s+1's 4 in flight (never drain
    // vmcnt to 0 in steady state — the whole point of R8)
    if (s < STEPS - 1) asm volatile("s_waitcnt vmcnt(4)" ::: "memory");
    else               asm volatile("s_waitcnt vmcnt(0)" ::: "memory");
    __builtin_amdgcn_sched_barrier(0);

    const float* buf = &tile_s[w][s & 1][0];
    const int ib = s * STEP_ROWS;      // row-in-wave base for this step

    #pragma unroll
    for (int j = 0; j < STEP_ROWS / 2; ++j) {
      const float4 x = *(const float4*)&buf[(2 * j + half) * ND + hl * 4];
      float d1 = x.x * qk1.x + x.y * qk1.y + x.z * qk1.z + x.w * qk1.w;
      float d2 = x.x * qk2.x + x.y * qk2.y + x.z * qk2.z + x.w * qk2.w;
      // packed-parity tree over the 32-lane half: interleave d1 (even lanes)
      // and d2 (odd lanes) after the xor-1 level -> 7 shuffles instead of 10
      float e1 = d1 + __shfl_xor(d1, 1, 64);
      float e2 = d2 + __shfl_xor(d2, 1, 64);
      float m = (lane & 1) ? e2 : e1;
      m += __shfl_xor(m, 2, 64);
      m += __shfl_xor(m, 4, 64);
      m += __shfl_xor(m, 8, 64);
      m += __shfl_xor(m, 16, 64);
      const float mo = __shfl_xor(m, 1, 64);
      const float s1 = (lane & 1) ? mo : m;
      const float s2 = (lane & 1) ? m : mo;
      const float pad = __shfl(pv, ib + 2 * j + half, 64);
      const float p1 = EXP2F(s1 + pad);
      const float p2 = EXP2F(s2 + pad);
      l1 += p1;
      l2 += p2;
      w1.x += p1 * x.x; w1.y += p1 * x.y; w1.z += p1 * x.z; w1.w += p1 * x.w;
      w2.x += p2 * x.x; w2.y += p2 * x.y; w2.z += p2 * x.z; w2.w += p2 * x.w;
    }

    // all ds_reads of this buffer retired before the DMA refill lands in it
    asm volatile("s_waitcnt lgkmcnt(0)" ::: "memory");
    if (s + 2 < STEPS) {
      const char* gs = gbase + (size_t)(s + 2) * STEP_BYTES + lane * 16;
      char* ls = (char*)&tile_s[w][s & 1][0];
      #pragma unroll
      for (int i = 0; i < 4; ++i)
        __builtin_amdgcn_global_load_lds(
            (gvoid_t*)(gs + i * 1024),
            (lvoid_t*)(ls + i * 1024), 16, 0, 0);
    }
  }

  // merge the two 32-lane halves within the wave
  l1 += __shfl_xor(l1, 32, 64);
  l2 += __shfl_xor(l2, 32, 64);
  w1.x += __shfl_xor(w1.x, 32, 64); w1.y += __shfl_xor(w1.y, 32, 64);
  w1.z += __shfl_xor(w1.z, 32, 64); w1.w += __shfl_xor(w1.w, 32, 64);
  w2.x += __shfl_xor(w2.x, 32, 64); w2.y += __shfl_xor(w2.y, 32, 64);
  w2.z += __shfl_xor(w2.z, 32, 64); w2.w += __shfl_xor(w2.w, 32, 64);
  if (half == 0) {
    *(float4*)&sw1[w][hl * 4] = w1;
    *(float4*)&sw2[w][hl * 4] = w2;
    if (hl == 0) { sl1[w] = l1; sl2[w] = l2; }
  }
  __syncthreads();   // the only block-wide barrier in the kernel

  float* po = part + (size_t)bid * PART_STRIDE;
  if (t == 0) {
    po[0] = sl1[0] + sl1[1] + sl1[2] + sl1[3];
    po[1] = sl2[0] + sl2[1] + sl2[2] + sl2[3];
  }
  if (t < ND) {
    po[4 + t]   = sw1[0][t] + sw1[1][t] + sw1[2][t] + sw1[3][t];
    po[132 + t] = sw2[0][t] + sw2[1][t] + sw2[2][t] + sw2[3][t];
  }
}

// ---------------------------------------------------------------------------
// Kernel 3: sum the NPART partials per batch, wd = W1/L1 - lam*W2/L2,
// z = wd @ Wv.T, then LayerNorm over OD=256. Grid: BB blocks, 256 threads.
// ---------------------------------------------------------------------------
__global__ __launch_bounds__(256) void finish_kernel(
    const float* __restrict__ part, const float* __restrict__ Wv,
    const float* __restrict__ lambda_logit, const float* __restrict__ gamma,
    const float* __restrict__ beta, float* __restrict__ out)
{
  const int b = blockIdx.x, t = threadIdx.x;
  __shared__ __align__(16) float wd_s[ND];
  __shared__ float red[8];

  const float lam = 0.8f + 0.2f / (1.f + __expf(-lambda_logit[0]));
  const float* pb = part + (size_t)b * NPART * PART_STRIDE;

  if (t < ND) {
    float L1 = 0.f, L2 = 0.f, W1 = 0.f, W2 = 0.f;
    #pragma unroll
    for (int i = 0; i < NPART; ++i) {
      const float* pc = pb + (size_t)i * PART_STRIDE;
      L1 += pc[0];
      L2 += pc[1];
      W1 += pc[4 + t];
      W2 += pc[132 + t];
    }
    wd_s[t] = W1 / L1 - lam * (W2 / L2);
  }
  __syncthreads();

  // z[o=t] = sum_d wd[d] * Wv[o,d]
  float z = 0.f;
  const float4* wvp = (const float4*)(Wv + t * ND);
  #pragma unroll 8
  for (int d = 0; d < ND / 4; ++d) {
    const float4 w = wvp[d];
    const float4 f = *(const float4*)&wd_s[d * 4];
    z += f.x * w.x + f.y * w.y + f.z * w.z + f.w * w.w;
  }

  // LayerNorm over the 256 outputs of this batch
  const int wave = t >> 6, lane = t & 63;
  float s = z;
  #pragma unroll
  for (int off = 32; off; off >>= 1) s += __shfl_xor(s, off, 64);
  if (lane == 0) red[wave] = s;
  __syncthreads();
  const float mu = (red[0] + red[1] + red[2] + red[3]) * (1.f / OD);
  const float dz = z - mu;
  float vs = dz * dz;
  #pragma unroll
  for (int off = 32; off; off >>= 1) vs += __shfl_xor(vs, off, 64);
  if (lane == 0) red[wave + 4] = vs;   // disjoint slots from red[0..3]
  __syncthreads();
  const float var = (red[4] + red[5] + red[6] + red[7]) * (1.f / OD);
  out[b * OD + t] = dz * rsqrtf(var + 1e-5f) * gamma[t] + beta[t];
}

// ---------------------------------------------------------------------------
extern "C" void kernel_launch(void* const* d_in, const int* in_sizes, int n_in,
                              void* d_out, int out_size, void* d_ws, size_t ws_size,
                              hipStream_t stream) {
  const float* fp_vec = (const float*)d_in[0];
  const float* node   = (const float*)d_in[1];
  const int*   mask   = (const int*)d_in[2];   // bool -> int32 per harness convention
  const float* Wq1    = (const float*)d_in[3];
  const float* Wq2    = (const float*)d_in[4];
  const float* Wk     = (const float*)d_in[5];
  const float* Wv     = (const float*)d_in[6];
  const float* ll     = (const float*)d_in[7];
  const float* gamma  = (const float*)d_in[8];
  const float* beta   = (const float*)d_in[9];
  float* out = (float*)d_out;

  // workspace layout (floats): qk1[B*128] | qk2[B*128] | partials[B*NPART*260]
  float* qk1g = (float*)d_ws;
  float* qk2g = qk1g + BB * ND;
  float* part = qk2g + BB * ND;

  proj_kernel<<<BB, 128, 0, stream>>>(fp_vec, Wq1, Wq2, Wk, qk1g, qk2g);
  attn_kernel<<<BB * NPART, 256, 0, stream>>>(node, mask, qk1g, qk2g, part);
  finish_kernel<<<BB, 256, 0, stream>>>(part, Wv, ll, gamma, beta, out);
}